// Round 1
// baseline (732.765 us; speedup 1.0000x reference)
//
#include <hip/hip_runtime.h>

// ---------------------------------------------------------------------------
// DMSRStyleConv v3: style-modulated, demodulated 3x3x3 conv.
// B=8, Cin=Cout=64, 48^3 -> 46^3 VALID, fp32 in/out.
//
//   1) s_kernel  : s[b][ci]  = style @ style_w^T + style_b      (512 blk x 64)
//   2) d_kernel  : d[b][co]  = rsqrt(sum (w*s)^2 + eps)         (512 blk x 64)
//   3) wq_kernel : wq[b][kc][tap][frag][lane][8] = bf16(w*s*d)  (216 blk x 256)
//                  -- MFMA-fragment order: lane-linear LDS stage + A-frag read
//   4) xT_kernel : xT[b][z][y][x][ci] = bf16(x)                 (13824 blk)
//   5) conv      : implicit GEMM, wave tile 64co x 64sp, K split in two
//                  32-ci chunks. Weights staged in 3-tap groups, double
//                  buffered, loads issued one group (48 MFMAs) ahead ->
//                  9 barriers per kc instead of 27 (T3/T4 amortization).
//                  LDS 51840(x) + 2*12288(w) = 76.4 KB -> 2 blocks/CU.
// ---------------------------------------------------------------------------

typedef __bf16 bf16x8 __attribute__((ext_vector_type(8)));
typedef float  f32x4  __attribute__((ext_vector_type(4)));

static constexpr int   B_   = 8;
static constexpr int   S_   = 512;
static constexpr int   G_   = 48;
static constexpr int   O_   = 46;
static constexpr int   TAPS = 27;
static constexpr int   SPI  = G_ * G_ * G_;   // 110592
static constexpr int   SPO  = O_ * O_ * O_;   // 97336
static constexpr float EPSV = 1e-8f;

// workspace layout (bytes)
static constexpr size_t XT_OFF   = 0;
static constexpr size_t XT_BYTES = (size_t)B_ * SPI * 64 * 2;        // 113 MB
static constexpr size_t WQ_OFF   = XT_OFF + XT_BYTES;
static constexpr size_t WQ_BYTES = (size_t)B_ * 2 * TAPS * 64 * 32 * 2; // 1.77 MB
static constexpr size_t S_OFF    = WQ_OFF + WQ_BYTES;
static constexpr size_t D_OFF    = S_OFF + 2048;

__device__ __forceinline__ unsigned short f2bf(float f) {
    unsigned int u = __float_as_uint(f);
    u = (u + 0x7fffu + ((u >> 16) & 1u)) >> 16;
    return (unsigned short)u;
}

// ---------------------------------------------------------------------------
// 1) s[b][g] = dot(style[b,:], style_w[g,:]) + style_b[g]; grid 512, block 64
// ---------------------------------------------------------------------------
__global__ void s_kernel(const float* __restrict__ style,
                         const float* __restrict__ style_w,
                         const float* __restrict__ style_b,
                         float* __restrict__ s_out)
{
    const int bg = blockIdx.x, b = bg >> 6, g = bg & 63, l = threadIdx.x;
    const float4* sp = (const float4*)(style + b * S_);
    const float4* wp = (const float4*)(style_w + g * S_);
    const float4 a0 = sp[l * 2], a1 = sp[l * 2 + 1];
    const float4 b0 = wp[l * 2], b1 = wp[l * 2 + 1];
    float acc = a0.x * b0.x + a0.y * b0.y + a0.z * b0.z + a0.w * b0.w
              + a1.x * b1.x + a1.y * b1.y + a1.z * b1.z + a1.w * b1.w;
#pragma unroll
    for (int m = 1; m <= 32; m <<= 1) acc += __shfl_xor(acc, m);
    if (l == 0) s_out[bg] = acc + style_b[g];
}

// ---------------------------------------------------------------------------
// 2) d[b][co] = rsqrt(sum_{ci,tap}(w[co][ci][tap]*s[b][ci])^2+eps); 512 x 64
// ---------------------------------------------------------------------------
__global__ void d_kernel(const float* __restrict__ weight,
                         const float* __restrict__ s,
                         float* __restrict__ d_out)
{
    const int bc = blockIdx.x, b = bc >> 6, co = bc & 63, ci = threadIdx.x;
    const float sv = s[b * 64 + ci];
    const float* wp = weight + (co * 64 + ci) * TAPS;
    float v = 0.f;
#pragma unroll
    for (int i = 0; i < TAPS; ++i) { const float t = wp[i] * sv; v += t * t; }
#pragma unroll
    for (int m = 1; m <= 32; m <<= 1) v += __shfl_xor(v, m);
    if (ci == 0) d_out[bc] = rsqrtf(v + EPSV);
}

// ---------------------------------------------------------------------------
// 3) wq in MFMA-fragment order. Per (b,kc,tap): 2048 bf16 laid out as
//    [frag g=0..3][lane l=0..63][8 shorts], where lane l of frag g holds
//    co = g*16 + (l&15), ci_local = (l>>4)*8 + j  (j=0..7).
//    This makes conv's weight stage (ds_write) and A-frag ds_read_b128
//    lane-linear (base + lane*16): conflict-free with no padding.
//    grid 216 (b,tap), block 256; each thread writes two uint4.
// ---------------------------------------------------------------------------
__global__ void wq_kernel(const float* __restrict__ weight,
                          const float* __restrict__ s,
                          const float* __restrict__ d,
                          unsigned short* __restrict__ wq)
{
    const int blk = blockIdx.x;
    const int b = blk / 27, tap = blk - b * 27;
    const int t = threadIdx.x;
#pragma unroll
    for (int it = 0; it < 2; ++it) {
        const int item = t + it * 256;          // 0..511 = kc*256 + g*64 + l
        const int kc = item >> 8;
        const int g  = (item >> 6) & 3;
        const int l  = item & 63;
        const int co = g * 16 + (l & 15);
        const int ci0 = kc * 32 + ((l >> 4) * 8);
        const float dd = d[b * 64 + co];
        unsigned int u[4];
#pragma unroll
        for (int k = 0; k < 4; ++k) {
            const int ci = ci0 + 2 * k;
            const float w0 = weight[(co * 64 + ci)     * TAPS + tap] * s[b * 64 + ci]     * dd;
            const float w1 = weight[(co * 64 + ci + 1) * TAPS + tap] * s[b * 64 + ci + 1] * dd;
            u[k] = (unsigned)f2bf(w0) | ((unsigned)f2bf(w1) << 16);
        }
        uint4 v; v.x = u[0]; v.y = u[1]; v.z = u[2]; v.w = u[3];
        *(uint4*)(wq + ((size_t)((b * 2 + kc) * 27 + tap)) * 2048 + (g * 64 + l) * 8) = v;
    }
}

// ---------------------------------------------------------------------------
// 4) x [b][ci][sp] fp32 -> xT [b][sp][ci] bf16; grid 8*1728, block 256
// ---------------------------------------------------------------------------
__global__ void xT_kernel(const float* __restrict__ x,
                          unsigned short* __restrict__ xT)
{
    const int blk = blockIdx.x;
    const int b = blk / 1728;
    const int sp0 = (blk - b * 1728) * 64;
    const int t = threadIdx.x;
    __shared__ float tile[64][65];

    const int spl = t & 63;
    const int c4 = t >> 6;
#pragma unroll
    for (int p = 0; p < 16; ++p) {
        const int ci = c4 * 16 + p;
        tile[ci][spl] = x[((size_t)b * 64 + ci) * SPI + sp0 + spl];
    }
    __syncthreads();

    const int ci8 = (t & 7) * 8;
    const int spq = t >> 3;                  // 0..31
#pragma unroll
    for (int p = 0; p < 2; ++p) {
        const int sp = spq + 32 * p;
        unsigned int u[4];
#pragma unroll
        for (int k = 0; k < 4; ++k) {
            const unsigned int lo = f2bf(tile[ci8 + 2 * k][sp]);
            const unsigned int hi = f2bf(tile[ci8 + 2 * k + 1][sp]);
            u[k] = lo | (hi << 16);
        }
        uint4 v; v.x = u[0]; v.y = u[1]; v.z = u[2]; v.w = u[3];
        *(uint4*)(xT + ((size_t)b * SPI + sp0 + sp) * 64 + ci8) = v;
    }
}

// ---------------------------------------------------------------------------
// 5) conv. Block = (b, 4z x 4y x 16x) outputs x 64 cout; 4 waves, each wave
//    = all 64 cout x 64 spatial (its z-slice). K (64 ci) split in 2 chunks
//    of 32; x-tile 18x6x6 sp x 32ci bf16, row stride 80 B (conflict-free).
//    Weights: 3-tap groups, double-buffered, fragment-order LDS (4 KB/tap,
//    no padding). Global loads for group g+2 issued while computing group g;
//    one barrier per group (48 MFMAs) instead of one per tap (16 MFMAs).
// ---------------------------------------------------------------------------
#define XST     80
#define XTILE_B (648 * 80)     // 51840
#define WGRP_B  (3 * 4096)     // 12288

__global__ __launch_bounds__(256, 2) void conv_kernel(
    const unsigned short* __restrict__ xT,   // [8][48][48][48][64] bf16 bits
    const unsigned short* __restrict__ wq,   // [8][2][27][4][64][8] bf16 bits
    const float* __restrict__ bias,          // [64]
    float* __restrict__ out)                 // [8][64][46][46][46] fp32
{
    __shared__ __align__(16) char lds[XTILE_B + 2 * WGRP_B];   // 76416 B
    char* const xs  = lds;
    char* const ws0 = lds + XTILE_B;

    const int t  = threadIdx.x;
    const int xt = blockIdx.x;               // 0..2
    const int yt = blockIdx.y;               // 0..11
    const int bz = blockIdx.z;               // 0..95
    const int b  = bz / 12, zt = bz - b * 12;
    const int x0 = xt * 16;                  // {0,16,32}; ox>=46 masked
    const int y0 = (yt < 11) ? yt * 4 : 42;  // overlap tiles: dup stores identical
    const int z0 = (zt < 11) ? zt * 4 : 42;

    const unsigned short* const xb = xT + (size_t)b * (SPI * 64);
    const unsigned short* const wb = wq + (size_t)b * (2 * TAPS * 2048);

    const int w = t >> 6, l = t & 63, kg = l >> 4, l16 = l & 15;
    const int bbase = (w * 108 + l16) * XST + kg * 16;   // B frag: dz=w, dx=l16

    f32x4 acc[16];
#pragma unroll
    for (int i = 0; i < 16; ++i) acc[i] = (f32x4){0.f, 0.f, 0.f, 0.f};

#pragma unroll 1
    for (int kc = 0; kc < 2; ++kc) {
        const unsigned short* const wkc = wb + (size_t)kc * (TAPS * 2048);

        // ---- stage x chunk: 648 sp x 32 ci --------------------------------
        for (int i = t; i < 2592; i += 256) {
            const int sp = i >> 2, cg = i & 3;
            const int iz = sp / 108;
            const int r1 = sp - iz * 108;
            const int iy = r1 / 18;
            const int ix = r1 - iy * 18;
            int gx = x0 + ix; if (gx > 47) gx = 47;      // clamp (masked outputs only)
            const uint4 v = *(const uint4*)(xb +
                ((((z0 + iz) * 48) + (y0 + iy)) * 48 + gx) * 64 + kc * 32 + cg * 8);
            *(uint4*)(xs + sp * XST + cg * 16) = v;
        }

        // ---- weight pipeline prologue: grp0 -> buf0, grp1 -> regs ---------
        uint4 pva[3];
#pragma unroll
        for (int j = 0; j < 3; ++j)
            pva[j] = *(const uint4*)(wkc + (size_t)j * 2048 + t * 8);
        __syncthreads();                     // x-tile visible; prior reads done
#pragma unroll
        for (int j = 0; j < 3; ++j)
            *(uint4*)(ws0 + j * 4096 + t * 16) = pva[j];
#pragma unroll
        for (int j = 0; j < 3; ++j)
            pva[j] = *(const uint4*)(wkc + (size_t)(3 + j) * 2048 + t * 8);
        __syncthreads();                     // buf0 weights visible

        int cur = 0;
#pragma unroll 1
        for (int grp = 0; grp < 9; ++grp) {
            // write group grp+1 (in regs) to the other buffer; issue grp+2
            if (grp < 8) {
                char* const wn = ws0 + (cur ^ 1) * WGRP_B;
#pragma unroll
                for (int j = 0; j < 3; ++j)
                    *(uint4*)(wn + j * 4096 + t * 16) = pva[j];
                if (grp < 7) {
#pragma unroll
                    for (int j = 0; j < 3; ++j)
                        pva[j] = *(const uint4*)(wkc +
                            (size_t)((grp + 2) * 3 + j) * 2048 + t * 8);
                }
            }

            const char* const wc = ws0 + cur * WGRP_B;
#pragma unroll
            for (int tl = 0; tl < 3; ++tl) {
                const int tap = grp * 3 + tl;
                const int kz = tap / 9;
                const int r2 = tap - kz * 9;
                const int ky = r2 / 3;
                const int kx = r2 - ky * 3;
                const int toff = ((kz * 6 + ky) * 18 + kx) * XST;

                bf16x8 a0 = *(const bf16x8*)(wc + tl * 4096 +        l * 16);
                bf16x8 a1 = *(const bf16x8*)(wc + tl * 4096 + 1024 + l * 16);
                bf16x8 a2 = *(const bf16x8*)(wc + tl * 4096 + 2048 + l * 16);
                bf16x8 a3 = *(const bf16x8*)(wc + tl * 4096 + 3072 + l * 16);
                bf16x8 b0 = *(const bf16x8*)(xs + toff + bbase);
                bf16x8 b1 = *(const bf16x8*)(xs + toff + bbase + 18 * XST);
                bf16x8 b2 = *(const bf16x8*)(xs + toff + bbase + 36 * XST);
                bf16x8 b3 = *(const bf16x8*)(xs + toff + bbase + 54 * XST);

                acc[0]  = __builtin_amdgcn_mfma_f32_16x16x32_bf16(a0, b0, acc[0],  0, 0, 0);
                acc[1]  = __builtin_amdgcn_mfma_f32_16x16x32_bf16(a0, b1, acc[1],  0, 0, 0);
                acc[2]  = __builtin_amdgcn_mfma_f32_16x16x32_bf16(a0, b2, acc[2],  0, 0, 0);
                acc[3]  = __builtin_amdgcn_mfma_f32_16x16x32_bf16(a0, b3, acc[3],  0, 0, 0);
                acc[4]  = __builtin_amdgcn_mfma_f32_16x16x32_bf16(a1, b0, acc[4],  0, 0, 0);
                acc[5]  = __builtin_amdgcn_mfma_f32_16x16x32_bf16(a1, b1, acc[5],  0, 0, 0);
                acc[6]  = __builtin_amdgcn_mfma_f32_16x16x32_bf16(a1, b2, acc[6],  0, 0, 0);
                acc[7]  = __builtin_amdgcn_mfma_f32_16x16x32_bf16(a1, b3, acc[7],  0, 0, 0);
                acc[8]  = __builtin_amdgcn_mfma_f32_16x16x32_bf16(a2, b0, acc[8],  0, 0, 0);
                acc[9]  = __builtin_amdgcn_mfma_f32_16x16x32_bf16(a2, b1, acc[9],  0, 0, 0);
                acc[10] = __builtin_amdgcn_mfma_f32_16x16x32_bf16(a2, b2, acc[10], 0, 0, 0);
                acc[11] = __builtin_amdgcn_mfma_f32_16x16x32_bf16(a2, b3, acc[11], 0, 0, 0);
                acc[12] = __builtin_amdgcn_mfma_f32_16x16x32_bf16(a3, b0, acc[12], 0, 0, 0);
                acc[13] = __builtin_amdgcn_mfma_f32_16x16x32_bf16(a3, b1, acc[13], 0, 0, 0);
                acc[14] = __builtin_amdgcn_mfma_f32_16x16x32_bf16(a3, b2, acc[14], 0, 0, 0);
                acc[15] = __builtin_amdgcn_mfma_f32_16x16x32_bf16(a3, b3, acc[15], 0, 0, 0);
            }
            __syncthreads();                 // writes visible; readers done
            cur ^= 1;
        }
    }

    // ---- epilogue: C/D col = l16 = dx (n), row = kg*4+r = co%16 -------------
    const size_t ob = (size_t)b * 64 * SPO;
    const int oz = z0 + w;
    const int ox = x0 + l16;
    const bool xok = (ox < O_);
    if (xok) {
#pragma unroll
        for (int g = 0; g < 4; ++g) {
#pragma unroll
            for (int nt = 0; nt < 4; ++nt) {
                const int oy = y0 + nt;
                const f32x4 v = acc[g * 4 + nt];
                const size_t so = (size_t)oz * 2116 + oy * 46 + ox;
#pragma unroll
                for (int r = 0; r < 4; ++r) {
                    const int co = g * 16 + kg * 4 + r;
                    out[ob + (size_t)co * SPO + so] = v[r] + bias[co];
                }
            }
        }
    }
}

// ---------------------------------------------------------------------------
extern "C" void kernel_launch(void* const* d_in, const int* in_sizes, int n_in,
                              void* d_out, int out_size, void* d_ws, size_t ws_size,
                              hipStream_t stream)
{
    const float* x       = (const float*)d_in[0];
    const float* style   = (const float*)d_in[1];
    const float* weight  = (const float*)d_in[2];
    const float* bias    = (const float*)d_in[3];
    const float* style_w = (const float*)d_in[4];
    const float* style_b = (const float*)d_in[5];
    float* out = (float*)d_out;

    char* ws = (char*)d_ws;
    unsigned short* xT  = (unsigned short*)(ws + XT_OFF);
    unsigned short* wqp = (unsigned short*)(ws + WQ_OFF);
    float* sbuf = (float*)(ws + S_OFF);
    float* dbuf = (float*)(ws + D_OFF);

    hipLaunchKernelGGL(s_kernel, dim3(512), dim3(64), 0, stream,
                       style, style_w, style_b, sbuf);
    hipLaunchKernelGGL(d_kernel, dim3(512), dim3(64), 0, stream,
                       weight, sbuf, dbuf);
    hipLaunchKernelGGL(wq_kernel, dim3(216), dim3(256), 0, stream,
                       weight, sbuf, dbuf, wqp);
    hipLaunchKernelGGL(xT_kernel, dim3(B_ * (SPI / 64)), dim3(256), 0, stream,
                       x, xT);
    hipLaunchKernelGGL(conv_kernel, dim3(3, 12, 96), dim3(256), 0, stream,
                       xT, wqp, bias, out);
}

// Round 2
// 588.904 us; speedup vs baseline: 1.2443x; 1.2443x over previous
//
#include <hip/hip_runtime.h>

// ---------------------------------------------------------------------------
// DMSRStyleConv v4: style-modulated, demodulated 3x3x3 conv.
// B=8, Cin=Cout=64, 48^3 -> 46^3 VALID, fp32 in/out.
//
//   1) s_kernel  : s[b][ci]  = style @ style_w^T + style_b      (512 blk x 64)
//   2) d_kernel  : d[b][co]  = rsqrt(sum (w*s)^2 + eps)         (512 blk x 64)
//   3) wq_kernel : wq[b][kc][tap][frag][lane][8] = bf16(w*s*d)  (216 blk x 256)
//   4) xT_kernel : xT[b][z][y][x][ci] = bf16(x)                 (13824 blk)
//   5) conv      : implicit GEMM, wave tile 64co x 64sp.
//        v4 changes (vs v3, 732 us, MfmaUtil 22%, Occ 22%):
//        - A-frags (weights) read DIRECTLY global->reg (wq is L2-resident,
//          fragment-order = lane-linear, coalesced 1KB/wave-instr).
//          LDS is x-only: 51.8 KB -> 3 blocks/CU (12 waves), 3 barriers/blk.
//        - XCD-bijective swizzle: grid 3456 = 8 XCD x 432; each XCD owns
//          exactly one batch b -> wq[b] + halos L2-local, output partial
//          cache lines (46-float rows, x-sibling blocks) merge in one L2
//          before writeback (WRITE_SIZE was 2.2x ideal).
// ---------------------------------------------------------------------------

typedef __bf16 bf16x8 __attribute__((ext_vector_type(8)));
typedef float  f32x4  __attribute__((ext_vector_type(4)));

static constexpr int   B_   = 8;
static constexpr int   S_   = 512;
static constexpr int   G_   = 48;
static constexpr int   O_   = 46;
static constexpr int   TAPS = 27;
static constexpr int   SPI  = G_ * G_ * G_;   // 110592
static constexpr int   SPO  = O_ * O_ * O_;   // 97336
static constexpr float EPSV = 1e-8f;

// workspace layout (bytes)
static constexpr size_t XT_OFF   = 0;
static constexpr size_t XT_BYTES = (size_t)B_ * SPI * 64 * 2;        // 113 MB
static constexpr size_t WQ_OFF   = XT_OFF + XT_BYTES;
static constexpr size_t WQ_BYTES = (size_t)B_ * 2 * TAPS * 64 * 32 * 2; // 1.77 MB
static constexpr size_t S_OFF    = WQ_OFF + WQ_BYTES;
static constexpr size_t D_OFF    = S_OFF + 2048;

__device__ __forceinline__ unsigned short f2bf(float f) {
    unsigned int u = __float_as_uint(f);
    u = (u + 0x7fffu + ((u >> 16) & 1u)) >> 16;
    return (unsigned short)u;
}

// ---------------------------------------------------------------------------
// 1) s[b][g] = dot(style[b,:], style_w[g,:]) + style_b[g]; grid 512, block 64
// ---------------------------------------------------------------------------
__global__ void s_kernel(const float* __restrict__ style,
                         const float* __restrict__ style_w,
                         const float* __restrict__ style_b,
                         float* __restrict__ s_out)
{
    const int bg = blockIdx.x, b = bg >> 6, g = bg & 63, l = threadIdx.x;
    const float4* sp = (const float4*)(style + b * S_);
    const float4* wp = (const float4*)(style_w + g * S_);
    const float4 a0 = sp[l * 2], a1 = sp[l * 2 + 1];
    const float4 b0 = wp[l * 2], b1 = wp[l * 2 + 1];
    float acc = a0.x * b0.x + a0.y * b0.y + a0.z * b0.z + a0.w * b0.w
              + a1.x * b1.x + a1.y * b1.y + a1.z * b1.z + a1.w * b1.w;
#pragma unroll
    for (int m = 1; m <= 32; m <<= 1) acc += __shfl_xor(acc, m);
    if (l == 0) s_out[bg] = acc + style_b[g];
}

// ---------------------------------------------------------------------------
// 2) d[b][co] = rsqrt(sum_{ci,tap}(w[co][ci][tap]*s[b][ci])^2+eps); 512 x 64
// ---------------------------------------------------------------------------
__global__ void d_kernel(const float* __restrict__ weight,
                         const float* __restrict__ s,
                         float* __restrict__ d_out)
{
    const int bc = blockIdx.x, b = bc >> 6, co = bc & 63, ci = threadIdx.x;
    const float sv = s[b * 64 + ci];
    const float* wp = weight + (co * 64 + ci) * TAPS;
    float v = 0.f;
#pragma unroll
    for (int i = 0; i < TAPS; ++i) { const float t = wp[i] * sv; v += t * t; }
#pragma unroll
    for (int m = 1; m <= 32; m <<= 1) v += __shfl_xor(v, m);
    if (ci == 0) d_out[bc] = rsqrtf(v + EPSV);
}

// ---------------------------------------------------------------------------
// 3) wq in MFMA-fragment order. Per (b,kc,tap): 2048 bf16 laid out as
//    [frag g=0..3][lane l=0..63][8 shorts], where lane l of frag g holds
//    co = g*16 + (l&15), ci_local = (l>>4)*8 + j  (j=0..7).
//    Lane-linear: conv reads A-frags straight from global, coalesced.
//    grid 216 (b,tap), block 256; each thread writes two uint4.
// ---------------------------------------------------------------------------
__global__ void wq_kernel(const float* __restrict__ weight,
                          const float* __restrict__ s,
                          const float* __restrict__ d,
                          unsigned short* __restrict__ wq)
{
    const int blk = blockIdx.x;
    const int b = blk / 27, tap = blk - b * 27;
    const int t = threadIdx.x;
#pragma unroll
    for (int it = 0; it < 2; ++it) {
        const int item = t + it * 256;          // 0..511 = kc*256 + g*64 + l
        const int kc = item >> 8;
        const int g  = (item >> 6) & 3;
        const int l  = item & 63;
        const int co = g * 16 + (l & 15);
        const int ci0 = kc * 32 + ((l >> 4) * 8);
        const float dd = d[b * 64 + co];
        unsigned int u[4];
#pragma unroll
        for (int k = 0; k < 4; ++k) {
            const int ci = ci0 + 2 * k;
            const float w0 = weight[(co * 64 + ci)     * TAPS + tap] * s[b * 64 + ci]     * dd;
            const float w1 = weight[(co * 64 + ci + 1) * TAPS + tap] * s[b * 64 + ci + 1] * dd;
            u[k] = (unsigned)f2bf(w0) | ((unsigned)f2bf(w1) << 16);
        }
        uint4 v; v.x = u[0]; v.y = u[1]; v.z = u[2]; v.w = u[3];
        *(uint4*)(wq + ((size_t)((b * 2 + kc) * 27 + tap)) * 2048 + (g * 64 + l) * 8) = v;
    }
}

// ---------------------------------------------------------------------------
// 4) x [b][ci][sp] fp32 -> xT [b][sp][ci] bf16; grid 8*1728, block 256
// ---------------------------------------------------------------------------
__global__ void xT_kernel(const float* __restrict__ x,
                          unsigned short* __restrict__ xT)
{
    const int blk = blockIdx.x;
    const int b = blk / 1728;
    const int sp0 = (blk - b * 1728) * 64;
    const int t = threadIdx.x;
    __shared__ float tile[64][65];

    const int spl = t & 63;
    const int c4 = t >> 6;
#pragma unroll
    for (int p = 0; p < 16; ++p) {
        const int ci = c4 * 16 + p;
        tile[ci][spl] = x[((size_t)b * 64 + ci) * SPI + sp0 + spl];
    }
    __syncthreads();

    const int ci8 = (t & 7) * 8;
    const int spq = t >> 3;                  // 0..31
#pragma unroll
    for (int p = 0; p < 2; ++p) {
        const int sp = spq + 32 * p;
        unsigned int u[4];
#pragma unroll
        for (int k = 0; k < 4; ++k) {
            const unsigned int lo = f2bf(tile[ci8 + 2 * k][sp]);
            const unsigned int hi = f2bf(tile[ci8 + 2 * k + 1][sp]);
            u[k] = lo | (hi << 16);
        }
        uint4 v; v.x = u[0]; v.y = u[1]; v.z = u[2]; v.w = u[3];
        *(uint4*)(xT + ((size_t)b * SPI + sp0 + sp) * 64 + ci8) = v;
    }
}

// ---------------------------------------------------------------------------
// 5) conv. Block = (b, 4z x 4y x 16x) outputs x 64 cout; 4 waves, each wave
//    = all 64 cout x 64 spatial (its z-slice). K (64 ci) split in 2 chunks
//    of 32; x-tile 18x6x6 sp x 32ci bf16, row stride 80 B.
//    A-frags: global->reg, double-buffered one tap ahead (L2-resident wq).
//    LDS = x-tile only (51.8 KB) -> 3 blocks/CU. 3 barriers per block.
// ---------------------------------------------------------------------------
#define XST     80
#define XTILE_B (648 * 80)     // 51840

__global__ __launch_bounds__(256, 3) void conv_kernel(
    const unsigned short* __restrict__ xT,   // [8][48][48][48][64] bf16 bits
    const unsigned short* __restrict__ wq,   // [8][2][27][4][64][8] bf16 bits
    const float* __restrict__ bias,          // [64]
    float* __restrict__ out)                 // [8][64][46][46][46] fp32
{
    __shared__ __align__(16) char xs[XTILE_B];

    const int t = threadIdx.x;
    // XCD-bijective swizzle: physical p -> XCD p%8 (round-robin); logical id
    // lg walks xt fastest, then yt, zt, b. 3456 = 8 * 432; 432 = one full b
    // (12 zt * 12 yt * 3 xt) -> each XCD owns exactly one batch.
    const int p  = blockIdx.x;
    const int lg = (p & 7) * 432 + (p >> 3);
    const int xt = lg % 3;                   // 0..2
    const int r0 = lg / 3;
    const int yt = r0 % 12;                  // 0..11
    const int bz = r0 / 12;                  // 0..95
    const int b  = bz / 12, zt = bz - b * 12;
    const int x0 = xt * 16;                  // {0,16,32}; ox>=46 masked
    const int y0 = (yt < 11) ? yt * 4 : 42;  // overlap tiles: dup stores identical
    const int z0 = (zt < 11) ? zt * 4 : 42;

    const unsigned short* const xb = xT + (size_t)b * (SPI * 64);
    const unsigned short* const wb = wq + (size_t)b * (2 * TAPS * 2048);

    const int w = t >> 6, l = t & 63, kg = l >> 4, l16 = l & 15;
    const int bbase = (w * 108 + l16) * XST + kg * 16;   // B frag: dz=w, dx=l16

    f32x4 acc[16];
#pragma unroll
    for (int i = 0; i < 16; ++i) acc[i] = (f32x4){0.f, 0.f, 0.f, 0.f};

#pragma unroll 1
    for (int kc = 0; kc < 2; ++kc) {
        const unsigned short* const wkc = wb + (size_t)kc * (TAPS * 2048);

        if (kc) __syncthreads();             // readers of prev x-tile done

        // ---- stage x chunk: 648 sp x 32 ci --------------------------------
        for (int i = t; i < 2592; i += 256) {
            const int sp = i >> 2, cg = i & 3;
            const int iz = sp / 108;
            const int r1 = sp - iz * 108;
            const int iy = r1 / 18;
            const int ix = r1 - iy * 18;
            int gx = x0 + ix; if (gx > 47) gx = 47;      // clamp (masked outputs only)
            const uint4 v = *(const uint4*)(xb +
                ((((z0 + iz) * 48) + (y0 + iy)) * 48 + gx) * 64 + kc * 32 + cg * 8);
            *(uint4*)(xs + sp * XST + cg * 16) = v;
        }

        // ---- prefetch A-frags for tap 0 (global->reg, lane-linear) --------
        bf16x8 a[4];
#pragma unroll
        for (int g = 0; g < 4; ++g)
            a[g] = *(const bf16x8*)(wkc + g * 512 + l * 8);

        __syncthreads();                     // x-tile visible

#pragma unroll 1
        for (int tap = 0; tap < TAPS; ++tap) {
            // prefetch next tap's A-frags (dup-load last tap; discarded)
            const int tnx = (tap + 1 < TAPS) ? tap + 1 : tap;
            bf16x8 an[4];
#pragma unroll
            for (int g = 0; g < 4; ++g)
                an[g] = *(const bf16x8*)(wkc + (size_t)tnx * 2048 + g * 512 + l * 8);

            const int kz = tap / 9;
            const int r2 = tap - kz * 9;
            const int ky = r2 / 3;
            const int kx = r2 - ky * 3;
            const int toff = ((kz * 6 + ky) * 18 + kx) * XST;

            bf16x8 b0 = *(const bf16x8*)(xs + toff + bbase);
            bf16x8 b1 = *(const bf16x8*)(xs + toff + bbase + 18 * XST);
            bf16x8 b2 = *(const bf16x8*)(xs + toff + bbase + 36 * XST);
            bf16x8 b3 = *(const bf16x8*)(xs + toff + bbase + 54 * XST);

            acc[0]  = __builtin_amdgcn_mfma_f32_16x16x32_bf16(a[0], b0, acc[0],  0, 0, 0);
            acc[1]  = __builtin_amdgcn_mfma_f32_16x16x32_bf16(a[0], b1, acc[1],  0, 0, 0);
            acc[2]  = __builtin_amdgcn_mfma_f32_16x16x32_bf16(a[0], b2, acc[2],  0, 0, 0);
            acc[3]  = __builtin_amdgcn_mfma_f32_16x16x32_bf16(a[0], b3, acc[3],  0, 0, 0);
            acc[4]  = __builtin_amdgcn_mfma_f32_16x16x32_bf16(a[1], b0, acc[4],  0, 0, 0);
            acc[5]  = __builtin_amdgcn_mfma_f32_16x16x32_bf16(a[1], b1, acc[5],  0, 0, 0);
            acc[6]  = __builtin_amdgcn_mfma_f32_16x16x32_bf16(a[1], b2, acc[6],  0, 0, 0);
            acc[7]  = __builtin_amdgcn_mfma_f32_16x16x32_bf16(a[1], b3, acc[7],  0, 0, 0);
            acc[8]  = __builtin_amdgcn_mfma_f32_16x16x32_bf16(a[2], b0, acc[8],  0, 0, 0);
            acc[9]  = __builtin_amdgcn_mfma_f32_16x16x32_bf16(a[2], b1, acc[9],  0, 0, 0);
            acc[10] = __builtin_amdgcn_mfma_f32_16x16x32_bf16(a[2], b2, acc[10], 0, 0, 0);
            acc[11] = __builtin_amdgcn_mfma_f32_16x16x32_bf16(a[2], b3, acc[11], 0, 0, 0);
            acc[12] = __builtin_amdgcn_mfma_f32_16x16x32_bf16(a[3], b0, acc[12], 0, 0, 0);
            acc[13] = __builtin_amdgcn_mfma_f32_16x16x32_bf16(a[3], b1, acc[13], 0, 0, 0);
            acc[14] = __builtin_amdgcn_mfma_f32_16x16x32_bf16(a[3], b2, acc[14], 0, 0, 0);
            acc[15] = __builtin_amdgcn_mfma_f32_16x16x32_bf16(a[3], b3, acc[15], 0, 0, 0);

#pragma unroll
            for (int g = 0; g < 4; ++g) a[g] = an[g];
        }
    }

    // ---- epilogue: C/D col = l16 = dx (n), row = kg*4+r = co%16 -------------
    const size_t ob = (size_t)b * 64 * SPO;
    const int oz = z0 + w;
    const int ox = x0 + l16;
    const bool xok = (ox < O_);
    if (xok) {
#pragma unroll
        for (int g = 0; g < 4; ++g) {
#pragma unroll
            for (int nt = 0; nt < 4; ++nt) {
                const int oy = y0 + nt;
                const f32x4 v = acc[g * 4 + nt];
                const size_t so = (size_t)oz * 2116 + oy * 46 + ox;
#pragma unroll
                for (int r = 0; r < 4; ++r) {
                    const int co = g * 16 + kg * 4 + r;
                    out[ob + (size_t)co * SPO + so] = v[r] + bias[co];
                }
            }
        }
    }
}

// ---------------------------------------------------------------------------
extern "C" void kernel_launch(void* const* d_in, const int* in_sizes, int n_in,
                              void* d_out, int out_size, void* d_ws, size_t ws_size,
                              hipStream_t stream)
{
    const float* x       = (const float*)d_in[0];
    const float* style   = (const float*)d_in[1];
    const float* weight  = (const float*)d_in[2];
    const float* bias    = (const float*)d_in[3];
    const float* style_w = (const float*)d_in[4];
    const float* style_b = (const float*)d_in[5];
    float* out = (float*)d_out;

    char* ws = (char*)d_ws;
    unsigned short* xT  = (unsigned short*)(ws + XT_OFF);
    unsigned short* wqp = (unsigned short*)(ws + WQ_OFF);
    float* sbuf = (float*)(ws + S_OFF);
    float* dbuf = (float*)(ws + D_OFF);

    hipLaunchKernelGGL(s_kernel, dim3(512), dim3(64), 0, stream,
                       style, style_w, style_b, sbuf);
    hipLaunchKernelGGL(d_kernel, dim3(512), dim3(64), 0, stream,
                       weight, sbuf, dbuf);
    hipLaunchKernelGGL(wq_kernel, dim3(216), dim3(256), 0, stream,
                       weight, sbuf, dbuf, wqp);
    hipLaunchKernelGGL(xT_kernel, dim3(B_ * (SPI / 64)), dim3(256), 0, stream,
                       x, xT);
    hipLaunchKernelGGL(conv_kernel, dim3(3456), dim3(256), 0, stream,
                       xT, wqp, bias, out);
}